// Round 1
// baseline (332.187 us; speedup 1.0000x reference)
//
#include <hip/hip_runtime.h>
#include <math.h>

// Problem constants (b=1, h=8, t=2048, d=64, n=32)
#define BH 8
#define NB 32
#define SS 64
#define DD 64
#define TT 2048

#define PAD 68   // float pad for 64-wide tiles (keeps float4 alignment, spreads banks)
#define WPAD 66  // pad for scalar-accessed weight buffer (conflict-free column reads)

// ---------------- Kernel 1: Sinkhorn R matrix -----------------------------
// One block per head (bh). 1024 threads = 32x32 matrix, thread (i,j).
__global__ __launch_bounds__(1024) void sinkhorn_kernel(
    const float* __restrict__ q, const float* __restrict__ k,
    const float* __restrict__ gu, float* __restrict__ Rm)
{
    __shared__ float qs[NB][65];
    __shared__ float ks[NB][65];
    __shared__ float rbuf[NB][33];

    const int bh = blockIdx.x;
    const int t  = threadIdx.x;
    const int i  = t >> 5;
    const int j  = t & 31;

    const float* qb = q + (size_t)bh * TT * DD;
    const float* kb = k + (size_t)bh * TT * DD;

    // bucket sums over s: qs[i][e] = sum_s qm[bh][i][s][e]
    for (int m = t; m < NB * DD; m += 1024) {
        int ii = m >> 6, e = m & 63;
        const float* qp = qb + (size_t)(ii * SS) * DD + e;
        const float* kp = kb + (size_t)(ii * SS) * DD + e;
        float sq_ = 0.f, sk_ = 0.f;
        for (int s = 0; s < SS; ++s) { sq_ += qp[(size_t)s * DD]; sk_ += kp[(size_t)s * DD]; }
        qs[ii][e] = sq_;
        ks[ii][e] = sk_;
    }
    __syncthreads();

    float acc = 0.f;
    for (int e = 0; e < DD; ++e) acc += qs[i][e] * ks[j][e];
    acc *= 0.125f;  // d^-0.5, d=64

    float r = logf(fmaxf(acc, 0.f) + 1e-6f);
    float u = gu[bh * NB * NB + t];
    float g = -logf(-logf(u + 1e-6f) + 1e-6f);
    r = (r + g) * (1.0f / 0.75f);

    for (int it = 0; it < 7; ++it) {
        // row LSE over j: lanes i*32..i*32+31 are contiguous -> width-32 butterfly
        float m = r;
        m = fmaxf(m, __shfl_xor(m, 16, 32));
        m = fmaxf(m, __shfl_xor(m, 8, 32));
        m = fmaxf(m, __shfl_xor(m, 4, 32));
        m = fmaxf(m, __shfl_xor(m, 2, 32));
        m = fmaxf(m, __shfl_xor(m, 1, 32));
        float s = expf(r - m);
        s += __shfl_xor(s, 16, 32);
        s += __shfl_xor(s, 8, 32);
        s += __shfl_xor(s, 4, 32);
        s += __shfl_xor(s, 2, 32);
        s += __shfl_xor(s, 1, 32);
        r -= m + logf(s);

        // col LSE over i: via LDS
        rbuf[i][j] = r;
        __syncthreads();
        float cm = -1e30f;
        for (int ii = 0; ii < NB; ++ii) cm = fmaxf(cm, rbuf[ii][j]);
        float cs = 0.f;
        for (int ii = 0; ii < NB; ++ii) cs += expf(rbuf[ii][j] - cm);
        r -= cm + logf(cs);
        __syncthreads();
    }

    float R = expf(r);
    Rm[bh * NB * NB + t] = (R > 1e-3f) ? R : 0.f;
}

// ---------------- Kernel 2: bucketed attention ----------------------------
// One block per (bh, q-bucket i). 256 threads: thread t -> query row sq=t>>2,
// quarter qtr=t&3 owning key-slice [qtr*16, qtr*16+16) and out-slice same.
__global__ __launch_bounds__(256) void attn_kernel(
    const float* __restrict__ q, const float* __restrict__ k,
    const float* __restrict__ v, const float* __restrict__ Rm,
    float* __restrict__ out)
{
    __shared__ float qls[SS][PAD];
    __shared__ float kbuf[SS][PAD];
    __shared__ float vbuf[SS][PAD];
    __shared__ float Wbuf[SS][WPAD];

    const int bh  = blockIdx.x >> 5;
    const int i   = blockIdx.x & 31;
    const int t   = threadIdx.x;
    const int sq  = t >> 2;
    const int qtr = t & 3;
    const int e0  = qtr * 16;

    const float* qb = q + ((size_t)bh * TT + (size_t)i * SS) * DD;

    // stage q tile and k_i tile
    for (int r = 0; r < 4; ++r) {
        int f = r * 256 + t;
        int row = f >> 4, c4 = (f & 15) << 2;
        *(float4*)&qls[row][c4] = ((const float4*)qb)[f];
    }
    {
        const float* kb = k + ((size_t)bh * TT + (size_t)i * SS) * DD;
        for (int r = 0; r < 4; ++r) {
            int f = r * 256 + t;
            int row = f >> 4, c4 = (f & 15) << 2;
            *(float4*)&kbuf[row][c4] = ((const float4*)kb)[f];
        }
    }
    __syncthreads();

    // self scores: S_self[sq][e0+kk], kept in registers (only this thread uses them)
    float sself[16];
#pragma unroll
    for (int kk = 0; kk < 16; ++kk) sself[kk] = 0.f;
    for (int e4 = 0; e4 < 16; ++e4) {
        float4 q4 = *(const float4*)&qls[sq][e4 << 2];
#pragma unroll
        for (int kk = 0; kk < 16; ++kk) {
            float4 k4 = *(const float4*)&kbuf[e0 + kk][e4 << 2];
            sself[kk] += q4.x * k4.x + q4.y * k4.y + q4.z * k4.z + q4.w * k4.w;
        }
    }
#pragma unroll
    for (int kk = 0; kk < 16; ++kk) sself[kk] *= 0.125f;

    float aAcc[16], outAcc[16];
#pragma unroll
    for (int kk = 0; kk < 16; ++kk) { aAcc[kk] = 0.f; outAcc[kk] = 0.f; }

    const float* Rrow = Rm + (size_t)bh * NB * NB + (size_t)i * NB;

    for (int j = 0; j < NB; ++j) {
        float rij = Rrow[j];          // uniform across the block
        if (rij == 0.f) continue;     // zero Rm => pair contributes nothing

        __syncthreads();              // previous iteration's LDS reads done
        const float* kb = k + ((size_t)bh * TT + (size_t)j * SS) * DD;
        const float* vb = v + ((size_t)bh * TT + (size_t)j * SS) * DD;
        for (int r = 0; r < 4; ++r) {
            int f = r * 256 + t;
            int row = f >> 4, c4 = (f & 15) << 2;
            *(float4*)&kbuf[row][c4] = ((const float4*)kb)[f];
            *(float4*)&vbuf[row][c4] = ((const float4*)vb)[f];
        }
        __syncthreads();

        // cross scores for this thread's 16 key columns
        float sc[16];
#pragma unroll
        for (int kk = 0; kk < 16; ++kk) sc[kk] = 0.f;
        for (int e4 = 0; e4 < 16; ++e4) {
            float4 q4 = *(const float4*)&qls[sq][e4 << 2];
#pragma unroll
            for (int kk = 0; kk < 16; ++kk) {
                float4 k4 = *(const float4*)&kbuf[e0 + kk][e4 << 2];
                sc[kk] += q4.x * k4.x + q4.y * k4.y + q4.z * k4.z + q4.w * k4.w;
            }
        }

        // softmax over concat [sself | sc] (128 vals per row, 32 per thread)
        float m = -1e30f;
#pragma unroll
        for (int kk = 0; kk < 16; ++kk) {
            sc[kk] *= 0.125f;
            m = fmaxf(m, sself[kk]);
            m = fmaxf(m, sc[kk]);
        }
        m = fmaxf(m, __shfl_xor(m, 1, 4));
        m = fmaxf(m, __shfl_xor(m, 2, 4));

        float wi[16], wj[16];
        float den = 0.f;
#pragma unroll
        for (int kk = 0; kk < 16; ++kk) {
            wi[kk] = expf(sself[kk] - m);
            wj[kk] = expf(sc[kk] - m);
            den += wi[kk] + wj[kk];
        }
        den += __shfl_xor(den, 1, 4);
        den += __shfl_xor(den, 2, 4);
        float wsc = rij / den;        // fold Rm into the weights

        // self-weights accumulate in registers (single PV_i matmul at the end)
#pragma unroll
        for (int kk = 0; kk < 16; ++kk) {
            aAcc[kk] += wi[kk] * wsc;
            Wbuf[sq][e0 + kk] = wj[kk] * wsc;
        }
        __syncthreads();

        // PV_j: out[sq][e0..e0+15] += sum_sk w_j[sq][sk] * v_j[sk][e]
        for (int sk = 0; sk < SS; ++sk) {
            float w = Wbuf[sq][sk];
#pragma unroll
            for (int c = 0; c < 4; ++c) {
                float4 v4 = *(const float4*)&vbuf[sk][e0 + (c << 2)];
                outAcc[c * 4 + 0] += w * v4.x;
                outAcc[c * 4 + 1] += w * v4.y;
                outAcc[c * 4 + 2] += w * v4.z;
                outAcc[c * 4 + 3] += w * v4.w;
            }
        }
    }

    // final PV_i: out += (sum_j Rm*w_i) @ v_i
    __syncthreads();
#pragma unroll
    for (int kk = 0; kk < 16; ++kk) Wbuf[sq][e0 + kk] = aAcc[kk];
    {
        const float* vb = v + ((size_t)bh * TT + (size_t)i * SS) * DD;
        for (int r = 0; r < 4; ++r) {
            int f = r * 256 + t;
            int row = f >> 4, c4 = (f & 15) << 2;
            *(float4*)&vbuf[row][c4] = ((const float4*)vb)[f];
        }
    }
    __syncthreads();
    for (int sk = 0; sk < SS; ++sk) {
        float w = Wbuf[sq][sk];
#pragma unroll
        for (int c = 0; c < 4; ++c) {
            float4 v4 = *(const float4*)&vbuf[sk][e0 + (c << 2)];
            outAcc[c * 4 + 0] += w * v4.x;
            outAcc[c * 4 + 1] += w * v4.y;
            outAcc[c * 4 + 2] += w * v4.z;
            outAcc[c * 4 + 3] += w * v4.w;
        }
    }

    float* ob = out + ((size_t)bh * TT + (size_t)i * SS) * DD;
#pragma unroll
    for (int c = 0; c < 4; ++c) {
        float4 o = make_float4(outAcc[c * 4 + 0], outAcc[c * 4 + 1],
                               outAcc[c * 4 + 2], outAcc[c * 4 + 3]);
        *(float4*)&ob[(size_t)sq * DD + e0 + (c << 2)] = o;
    }
}

extern "C" void kernel_launch(void* const* d_in, const int* in_sizes, int n_in,
                              void* d_out, int out_size, void* d_ws, size_t ws_size,
                              hipStream_t stream) {
    (void)in_sizes; (void)n_in; (void)out_size; (void)ws_size;
    const float* q  = (const float*)d_in[0];
    const float* k  = (const float*)d_in[1];
    const float* v  = (const float*)d_in[2];
    const float* gu = (const float*)d_in[3];
    float* Rm  = (float*)d_ws;           // 8*32*32 floats = 32 KB scratch
    float* out = (float*)d_out;

    sinkhorn_kernel<<<BH, 1024, 0, stream>>>(q, k, gu, Rm);
    attn_kernel<<<BH * NB, 256, 0, stream>>>(q, k, v, Rm, out);
}

// Round 2
// 67.766 us; speedup vs baseline: 4.9020x; 4.9020x over previous
//
#include <hip/hip_runtime.h>
#include <math.h>
#include <stdint.h>

// Problem constants (b=1, h=8, t=2048, d=64, n=32)
#define BH 8
#define NB 32
#define SS 64
#define DD 64
#define TT 2048

typedef float f32x16 __attribute__((ext_vector_type(16)));
typedef short bf16x8 __attribute__((ext_vector_type(8)));
typedef unsigned short u16;

__device__ __forceinline__ unsigned pkbf(float a, float b) {
  unsigned r;
  asm("v_cvt_pk_bf16_f32 %0, %1, %2" : "=v"(r) : "v"(a), "v"(b));
  return r;
}
__device__ __forceinline__ float exp2x(float x) {
  float r;
  asm("v_exp_f32 %0, %1" : "=v"(r) : "v"(x));
  return r;
}
// pack 8 consecutive f32 elements [b..b+7] of a f32x16 into a bf16x8 frag
__device__ __forceinline__ bf16x8 pack8v(const f32x16& v, const int b) {
  union { unsigned u[4]; bf16x8 v8; } x;
  x.u[0] = pkbf(v[b + 0], v[b + 1]);
  x.u[1] = pkbf(v[b + 2], v[b + 3]);
  x.u[2] = pkbf(v[b + 4], v[b + 5]);
  x.u[3] = pkbf(v[b + 6], v[b + 7]);
  return x.v8;
}

// ---------------- Kernel 1: prep (bf16 convert + permute + VT + bucket sums) ----
// blocks 0..255: (bh,bucket) -> VT permuted + q/k column sums
// blocks 256..383: q convert (scaled by 0.125*log2e), permuted fragment layout
// blocks 384..511: k convert, permuted fragment layout
// permuted row layout: within a 64-elem row, out[16s+8hi+e] = in[16s+4hi+(e&3)+8(e>>2)]
__global__ __launch_bounds__(256) void prep_kernel(
    const float* __restrict__ q, const float* __restrict__ k, const float* __restrict__ v,
    u16* __restrict__ qb, u16* __restrict__ kb, u16* __restrict__ vtb,
    float* __restrict__ qsum, float* __restrict__ ksum)
{
  const int bid = blockIdx.x;
  const int t = threadIdx.x;
  if (bid < 256) {
    __shared__ float vt[SS][68];
    const float* vb = v + (size_t)bid * 4096;
#pragma unroll
    for (int r4 = 0; r4 < 4; ++r4) {
      int f = r4 * 256 + t;
      int row = f >> 4, c4 = (f & 15) << 2;
      *(float4*)&vt[row][c4] = ((const float4*)vb)[f];
    }
    __syncthreads();
    {
      int d = t >> 2;
      int cb = (t & 3) * 2;
      u16* dst = vtb + (size_t)bid * 4096 + d * 64 + cb * 8;
#pragma unroll
      for (int cc = 0; cc < 2; ++cc) {
        int c = cb + cc;
        int s = c >> 1, hi = c & 1;
        int kb0 = 16 * s + 4 * hi;
        uint4 o;
        o.x = pkbf(vt[kb0 + 0][d], vt[kb0 + 1][d]);
        o.y = pkbf(vt[kb0 + 2][d], vt[kb0 + 3][d]);
        o.z = pkbf(vt[kb0 + 8][d], vt[kb0 + 9][d]);
        o.w = pkbf(vt[kb0 + 10][d], vt[kb0 + 11][d]);
        *(uint4*)(dst + cc * 8) = o;
      }
    }
    if (t < 64) {
      const float* qp = q + (size_t)bid * 4096 + t;
      float s = 0.f;
#pragma unroll 8
      for (int r = 0; r < 64; ++r) s += qp[r * 64];
      qsum[bid * 64 + t] = s;
    } else if (t < 128) {
      const float* kp = k + (size_t)bid * 4096 + (t - 64);
      float s = 0.f;
#pragma unroll 8
      for (int r = 0; r < 64; ++r) s += kp[r * 64];
      ksum[bid * 64 + (t - 64)] = s;
    }
  } else {
    const bool isQ = bid < 384;
    const float* src = isQ ? q : k;
    u16* dst = isQ ? qb : kb;
    const float scale = isQ ? 0.18033688011112042f : 1.0f;  // 0.125 * log2(e)
    const int blk = bid - (isQ ? 256 : 384);                // 0..127
#pragma unroll
    for (int it = 0; it < 4; ++it) {
      int chunk = blk * 1024 + it * 256 + t;  // 8-elem output chunk id
      int r = chunk >> 3, sub = chunk & 7;
      int s = sub >> 1, hi = sub & 1;
      const float* ip = src + (size_t)r * 64 + 16 * s + 4 * hi;
      float4 a = *(const float4*)(ip);
      float4 b = *(const float4*)(ip + 8);
      uint4 o;
      o.x = pkbf(a.x * scale, a.y * scale);
      o.y = pkbf(a.z * scale, a.w * scale);
      o.z = pkbf(b.x * scale, b.y * scale);
      o.w = pkbf(b.z * scale, b.w * scale);
      *(uint4*)(dst + (size_t)chunk * 8) = o;
    }
  }
}

// ---------------- Kernel 2: Sinkhorn R matrix -----------------------------
__global__ __launch_bounds__(1024) void sinkhorn_kernel(
    const float* __restrict__ qsum, const float* __restrict__ ksum,
    const float* __restrict__ gu, float* __restrict__ Rm)
{
  __shared__ float qs[NB][65];
  __shared__ float ks[NB][65];
  __shared__ float rbuf[NB][33];

  const int bh = blockIdx.x;
  const int t  = threadIdx.x;
  const int i  = t >> 5;
  const int j  = t & 31;

  for (int m = t; m < NB * DD; m += 1024) {
    qs[m >> 6][m & 63] = qsum[bh * 2048 + m];
    ks[m >> 6][m & 63] = ksum[bh * 2048 + m];
  }
  __syncthreads();

  float acc = 0.f;
  for (int e = 0; e < DD; ++e) acc += qs[i][e] * ks[j][e];
  acc *= 0.125f;

  float r = logf(fmaxf(acc, 0.f) + 1e-6f);
  float u = gu[bh * NB * NB + t];
  float g = -logf(-logf(u + 1e-6f) + 1e-6f);
  r = (r + g) * (1.0f / 0.75f);

  for (int it = 0; it < 7; ++it) {
    float m = r;
    m = fmaxf(m, __shfl_xor(m, 16, 32));
    m = fmaxf(m, __shfl_xor(m, 8, 32));
    m = fmaxf(m, __shfl_xor(m, 4, 32));
    m = fmaxf(m, __shfl_xor(m, 2, 32));
    m = fmaxf(m, __shfl_xor(m, 1, 32));
    float s = expf(r - m);
    s += __shfl_xor(s, 16, 32);
    s += __shfl_xor(s, 8, 32);
    s += __shfl_xor(s, 4, 32);
    s += __shfl_xor(s, 2, 32);
    s += __shfl_xor(s, 1, 32);
    r -= m + logf(s);

    rbuf[i][j] = r;
    __syncthreads();
    float cm = -1e30f;
    for (int ii = 0; ii < NB; ++ii) cm = fmaxf(cm, rbuf[ii][j]);
    float cs = 0.f;
    for (int ii = 0; ii < NB; ++ii) cs += expf(rbuf[ii][j] - cm);
    r -= cm + logf(cs);
    __syncthreads();
  }

  float R = expf(r);
  Rm[bh * NB * NB + t] = (R > 1e-3f) ? R : 0.f;
}

// ---------------- Kernel 3: MFMA bucketed attention -----------------------
// block per (bh, i): 512 threads = 8 waves; wave w handles j in {w, w+8, w+16, w+24}
__global__ __launch_bounds__(512) void attn_kernel(
    const u16* __restrict__ qb, const u16* __restrict__ kb,
    const u16* __restrict__ vtb, const float* __restrict__ Rm,
    float* __restrict__ out)
{
  __shared__ float red[4][64][68];
  __shared__ float cbuf[8][64];

  const int bh  = blockIdx.x >> 5;
  const int i   = blockIdx.x & 31;
  const int t   = threadIdx.x;
  const int w   = t >> 6;
  const int lane = t & 63;
  const int l31 = lane & 31;
  const int hi  = lane >> 5;

  const u16* qbase = qb + ((size_t)bh * TT + i * SS) * DD;
  const u16* kbh   = kb + (size_t)bh * TT * DD;
  const u16* vbh   = vtb + (size_t)bh * TT * DD;

  // Q B-fragments (persistent)
  bf16x8 qB[2][4];
#pragma unroll
  for (int n = 0; n < 2; ++n)
#pragma unroll
    for (int s = 0; s < 4; ++s)
      qB[n][s] = *(const bf16x8*)(qbase + (l31 + 32 * n) * 64 + 16 * s + 8 * hi);

  // ---- self scores S^T = K_i * Q^T ----
  f32x16 accS[2][2];
#pragma unroll
  for (int m = 0; m < 2; ++m)
#pragma unroll
    for (int n = 0; n < 2; ++n)
#pragma unroll
      for (int e = 0; e < 16; ++e) accS[m][n][e] = 0.f;
  {
    const u16* kib = kbh + (size_t)i * SS * DD;
    bf16x8 kA[2][4];
#pragma unroll
    for (int m = 0; m < 2; ++m)
#pragma unroll
      for (int s = 0; s < 4; ++s)
        kA[m][s] = *(const bf16x8*)(kib + (l31 + 32 * m) * 64 + 16 * s + 8 * hi);
#pragma unroll
    for (int s = 0; s < 4; ++s)
#pragma unroll
      for (int m = 0; m < 2; ++m)
#pragma unroll
        for (int n = 0; n < 2; ++n)
          accS[m][n] = __builtin_amdgcn_mfma_f32_32x32x16_bf16(kA[m][s], qB[n][s], accS[m][n], 0, 0, 0);
  }

  // ---- softmax prep on self: m0, S0, P_self = exp2(S - m0) packed to A-frags ----
  float m0[2], S0[2];
  bf16x8 psA[2][4];
#pragma unroll
  for (int n = 0; n < 2; ++n) {
    float mx[16];
#pragma unroll
    for (int r = 0; r < 16; ++r) mx[r] = fmaxf(accS[0][n][r], accS[1][n][r]);
#pragma unroll
    for (int off = 8; off > 0; off >>= 1)
#pragma unroll
      for (int r = 0; r < off; ++r) mx[r] = fmaxf(mx[r], mx[r + off]);
    float mm = fmaxf(mx[0], __shfl_xor(mx[0], 32, 64));
    float sm[16];
#pragma unroll
    for (int m = 0; m < 2; ++m)
#pragma unroll
      for (int r = 0; r < 16; ++r) accS[m][n][r] = exp2x(accS[m][n][r] - mm);
#pragma unroll
    for (int r = 0; r < 16; ++r) sm[r] = accS[0][n][r] + accS[1][n][r];
#pragma unroll
    for (int off = 8; off > 0; off >>= 1)
#pragma unroll
      for (int r = 0; r < off; ++r) sm[r] += sm[r + off];
    float ss = sm[0] + __shfl_xor(sm[0], 32, 64);
    m0[n] = mm;
    S0[n] = ss;
    psA[n][0] = pack8v(accS[0][n], 0);
    psA[n][1] = pack8v(accS[0][n], 8);
    psA[n][2] = pack8v(accS[1][n], 0);
    psA[n][3] = pack8v(accS[1][n], 8);
  }

  // ---- j loop ----
  f32x16 outAcc[2][2];
#pragma unroll
  for (int m = 0; m < 2; ++m)
#pragma unroll
    for (int n = 0; n < 2; ++n)
#pragma unroll
      for (int e = 0; e < 16; ++e) outAcc[m][n][e] = 0.f;
  float cacc[2] = {0.f, 0.f};
  const float* Rrow = Rm + bh * NB * NB + i * NB;

  for (int j = w; j < NB; j += 8) {
    float rij = Rrow[j];
    if (rij == 0.f) continue;
    const u16* kjb = kbh + (size_t)j * SS * DD;
    const u16* vjb = vbh + (size_t)j * SS * DD;

    bf16x8 kA[2][4];
#pragma unroll
    for (int m = 0; m < 2; ++m)
#pragma unroll
      for (int s = 0; s < 4; ++s)
        kA[m][s] = *(const bf16x8*)(kjb + (l31 + 32 * m) * 64 + 16 * s + 8 * hi);

    f32x16 acc[2][2];
#pragma unroll
    for (int m = 0; m < 2; ++m)
#pragma unroll
      for (int n = 0; n < 2; ++n)
#pragma unroll
        for (int e = 0; e < 16; ++e) acc[m][n][e] = 0.f;
#pragma unroll
    for (int s = 0; s < 4; ++s)
#pragma unroll
      for (int m = 0; m < 2; ++m)
#pragma unroll
        for (int n = 0; n < 2; ++n)
          acc[m][n] = __builtin_amdgcn_mfma_f32_32x32x16_bf16(kA[m][s], qB[n][s], acc[m][n], 0, 0, 0);

    bf16x8 vB[2][4];
#pragma unroll
    for (int n = 0; n < 2; ++n)
#pragma unroll
      for (int s = 0; s < 4; ++s)
        vB[n][s] = *(const bf16x8*)(vjb + (l31 + 32 * n) * 64 + 16 * s + 8 * hi);

    // softmax over concat [self | cross], log2-domain
    float wsc[2];
#pragma unroll
    for (int n = 0; n < 2; ++n) {
      float mx[16];
#pragma unroll
      for (int r = 0; r < 16; ++r) mx[r] = fmaxf(acc[0][n][r], acc[1][n][r]);
#pragma unroll
      for (int off = 8; off > 0; off >>= 1)
#pragma unroll
        for (int r = 0; r < off; ++r) mx[r] = fmaxf(mx[r], mx[r + off]);
      float mc = fmaxf(mx[0], __shfl_xor(mx[0], 32, 64));
      float mj = fmaxf(m0[n], mc);
      float sm[16];
#pragma unroll
      for (int m = 0; m < 2; ++m)
#pragma unroll
        for (int r = 0; r < 16; ++r) acc[m][n][r] = exp2x(acc[m][n][r] - mj);
#pragma unroll
      for (int r = 0; r < 16; ++r) sm[r] = acc[0][n][r] + acc[1][n][r];
#pragma unroll
      for (int off = 8; off > 0; off >>= 1)
#pragma unroll
        for (int r = 0; r < off; ++r) sm[r] += sm[r + off];
      float ssum = sm[0] + __shfl_xor(sm[0], 32, 64);
      float e0 = exp2x(m0[n] - mj);
      float den = S0[n] * e0 + ssum;
      float inv = rij / den;
      wsc[n] = inv;
      cacc[n] += e0 * inv;
    }
#pragma unroll
    for (int m = 0; m < 2; ++m)
#pragma unroll
      for (int n = 0; n < 2; ++n)
#pragma unroll
        for (int r = 0; r < 16; ++r) acc[m][n][r] *= wsc[n];

    // PV_j: out += W @ V_j   (W A-frags packed in-lane)
#pragma unroll
    for (int s = 0; s < 4; ++s) {
      bf16x8 w0 = pack8v(acc[s >> 1][0], 8 * (s & 1));
      bf16x8 w1 = pack8v(acc[s >> 1][1], 8 * (s & 1));
#pragma unroll
      for (int n = 0; n < 2; ++n) {
        outAcc[0][n] = __builtin_amdgcn_mfma_f32_32x32x16_bf16(w0, vB[n][s], outAcc[0][n], 0, 0, 0);
        outAcc[1][n] = __builtin_amdgcn_mfma_f32_32x32x16_bf16(w1, vB[n][s], outAcc[1][n], 0, 0, 0);
      }
    }
  }

  // ---- self PV: out += diag(cacc) * P_self @ V_i ----
  f32x16 U[2][2];
#pragma unroll
  for (int m = 0; m < 2; ++m)
#pragma unroll
    for (int n = 0; n < 2; ++n)
#pragma unroll
      for (int e = 0; e < 16; ++e) U[m][n][e] = 0.f;
  {
    const u16* vib = vbh + (size_t)i * SS * DD;
    bf16x8 vBi[2][4];
#pragma unroll
    for (int n = 0; n < 2; ++n)
#pragma unroll
      for (int s = 0; s < 4; ++s)
        vBi[n][s] = *(const bf16x8*)(vib + (l31 + 32 * n) * 64 + 16 * s + 8 * hi);
#pragma unroll
    for (int s = 0; s < 4; ++s)
#pragma unroll
      for (int mq = 0; mq < 2; ++mq)
#pragma unroll
        for (int n = 0; n < 2; ++n)
          U[mq][n] = __builtin_amdgcn_mfma_f32_32x32x16_bf16(psA[mq][s], vBi[n][s], U[mq][n], 0, 0, 0);
  }
  if (hi == 0) {
    cbuf[w][l31] = cacc[0];
    cbuf[w][l31 + 32] = cacc[1];
  }
  __syncthreads();
#pragma unroll
  for (int mq = 0; mq < 2; ++mq)
#pragma unroll
    for (int r = 0; r < 16; ++r) {
      int row = (r & 3) + 8 * (r >> 2) + 4 * hi + 32 * mq;
      float cr = cbuf[w][row];
#pragma unroll
      for (int n = 0; n < 2; ++n) outAcc[mq][n][r] += U[mq][n][r] * cr;
    }

  // ---- cross-wave tree reduction ----
#define RED_W(buf)                                                         \
  {                                                                        \
    _Pragma("unroll") for (int mq = 0; mq < 2; ++mq)                       \
    _Pragma("unroll") for (int n = 0; n < 2; ++n)                          \
    _Pragma("unroll") for (int r = 0; r < 16; ++r) {                       \
      int row = (r & 3) + 8 * (r >> 2) + 4 * hi + 32 * mq;                 \
      (buf)[row][l31 + 32 * n] = outAcc[mq][n][r];                         \
    }                                                                      \
  }
#define RED_A(buf)                                                         \
  {                                                                        \
    _Pragma("unroll") for (int mq = 0; mq < 2; ++mq)                       \
    _Pragma("unroll") for (int n = 0; n < 2; ++n)                          \
    _Pragma("unroll") for (int r = 0; r < 16; ++r) {                       \
      int row = (r & 3) + 8 * (r >> 2) + 4 * hi + 32 * mq;                 \
      outAcc[mq][n][r] += (buf)[row][l31 + 32 * n];                        \
    }                                                                      \
  }

  if (w >= 4) RED_W(red[w - 4]);
  __syncthreads();
  if (w < 4) RED_A(red[w]);
  __syncthreads();
  if (w == 2 || w == 3) RED_W(red[w - 2]);
  __syncthreads();
  if (w < 2) RED_A(red[w]);
  __syncthreads();
  if (w == 1) RED_W(red[0]);
  __syncthreads();
  if (w == 0) {
    RED_A(red[0]);
    RED_W(red[0]);
  }
  __syncthreads();

  // coalesced store
  {
    int row = t >> 3;
    int col0 = (t & 7) * 8;
    float4 a = *(const float4*)&red[0][row][col0];
    float4 b = *(const float4*)&red[0][row][col0 + 4];
    float* ob = out + ((size_t)bh * TT + i * SS + row) * DD + col0;
    *(float4*)ob = a;
    *(float4*)(ob + 4) = b;
  }
}

extern "C" void kernel_launch(void* const* d_in, const int* in_sizes, int n_in,
                              void* d_out, int out_size, void* d_ws, size_t ws_size,
                              hipStream_t stream) {
  (void)in_sizes; (void)n_in; (void)out_size; (void)ws_size;
  const float* q  = (const float*)d_in[0];
  const float* k  = (const float*)d_in[1];
  const float* v  = (const float*)d_in[2];
  const float* gu = (const float*)d_in[3];
  float* out = (float*)d_out;

  char* wsb = (char*)d_ws;
  u16* qb   = (u16*)(wsb);
  u16* kb   = (u16*)(wsb + (1 << 21));
  u16* vtb  = (u16*)(wsb + (2 << 21));
  float* qsum = (float*)(wsb + (3 << 21));
  float* ksum = (float*)(wsb + (3 << 21) + (1 << 16));
  float* Rm   = (float*)(wsb + (3 << 21) + (2 << 16));

  prep_kernel<<<512, 256, 0, stream>>>(q, k, v, qb, kb, vtb, qsum, ksum);
  sinkhorn_kernel<<<BH, 1024, 0, stream>>>(qsum, ksum, gu, Rm);
  attn_kernel<<<BH * NB, 512, 0, stream>>>(qb, kb, vtb, Rm, out);
}